// Round 14
// baseline (2021.206 us; speedup 1.0000x reference)
//
#include <hip/hip_runtime.h>
#include <hip/hip_cooperative_groups.h>
#include <math.h>

namespace cg = cooperative_groups;

// Problem constants
#define B_  32
#define C_  256
#define H_  56
#define W_  56
#define CR_ 64          // C/RED
#define HW_ (H_*W_)     // 3136
#define BC_ (B_*C_)     // 8192

#define PPB   4         // planes per block (coop kernel)
#define GRID_ (BC_/PPB) // 2048 blocks = 8/CU on 256 CUs

typedef float float2v __attribute__((ext_vector_type(2)));

__device__ __forceinline__ float2v pk_fma(float2v a, float2v b, float2v c) {
    float2v d;
    asm("v_pk_fma_f32 %0, %1, %2, %3" : "=v"(d) : "v"(a), "v"(b), "v"(c));
    return d;
}

__device__ __forceinline__ float ld_agent(const float* p) {
    return __hip_atomic_load(p, __ATOMIC_ACQUIRE, __HIP_MEMORY_SCOPE_AGENT);
}
__device__ __forceinline__ void st_agent(float* p, float v) {
    __hip_atomic_store(p, v, __ATOMIC_RELEASE, __HIP_MEMORY_SCOPE_AGENT);
}

// softmax over 9 logits (per-thread, redundant) then pk_fma conv from LDS.
__device__ __forceinline__ void conv_plane(const float* __restrict__ sm,
                                           const float* __restrict__ lg,
                                           float* __restrict__ o, int tid) {
    float l0 = lg[0], l1 = lg[1], l2 = lg[2], l3 = lg[3], l4 = lg[4],
          l5 = lg[5], l6 = lg[6], l7 = lg[7], l8 = lg[8];
    float mx = fmaxf(fmaxf(fmaxf(fmaxf(l0, l1), fmaxf(l2, l3)),
                           fmaxf(fmaxf(l4, l5), fmaxf(l6, l7))), l8);
    float k0 = __expf(l0 - mx), k1 = __expf(l1 - mx), k2 = __expf(l2 - mx),
          k3 = __expf(l3 - mx), k4 = __expf(l4 - mx), k5 = __expf(l5 - mx),
          k6 = __expf(l6 - mx), k7 = __expf(l7 - mx), k8 = __expf(l8 - mx);
    const float inv = 1.0f / (((k0 + k1) + (k2 + k3)) + ((k4 + k5) + (k6 + k7)) + k8);
    k0 *= inv; k1 *= inv; k2 *= inv; k3 *= inv; k4 *= inv;
    k5 *= inv; k6 *= inv; k7 *= inv; k8 *= inv;

    const float2v K0 = {k0, k0}, K1 = {k1, k1}, K2 = {k2, k2};
    const float2v K3 = {k3, k3}, K4 = {k4, k4}, K5 = {k5, k5};
    const float2v K6 = {k6, k6}, K7 = {k7, k7}, K8 = {k8, k8};

    if (tid < 224) {
        const int s  = tid / 28;
        const int g  = tid - s * 28;
        const int y0 = s * 7;
        const float* base = sm + y0 * 64 + 3 + 2 * g;

        float a0 = base[0], a1 = base[1], a2 = base[2], a3 = base[3];
        const float* rB = base + 64;
        float b0 = rB[0], b1 = rB[1], b2 = rB[2], b3 = rB[3];

        #pragma unroll
        for (int r = 0; r < 7; ++r) {
            const float* rC = base + (r + 2) * 64;
            const float c0v = rC[0], c1v = rC[1], c2v = rC[2], c3v = rC[3];

            const float2v Am = {a0, a1}, A0 = {a1, a2}, Ap = {a2, a3};
            const float2v Bm = {b0, b1}, B0 = {b1, b2}, Bp = {b2, b3};
            const float2v Cm = {c0v, c1v}, C0 = {c1v, c2v}, Cp = {c2v, c3v};

            float2v acc = B0;                    // residual
            acc = pk_fma(K0, Am, acc);
            acc = pk_fma(K1, A0, acc);
            acc = pk_fma(K2, Ap, acc);
            acc = pk_fma(K3, Bm, acc);
            acc = pk_fma(K4, B0, acc);
            acc = pk_fma(K5, Bp, acc);
            acc = pk_fma(K6, Cm, acc);
            acc = pk_fma(K7, C0, acc);
            acc = pk_fma(K8, Cp, acc);

            *(float2v*)(o + (y0 + r) * W_ + 2 * g) = acc;

            a0 = b0; a1 = b1; a2 = b2; a3 = b3;
            b0 = c0v; b1 = c1v; b2 = c2v; b3 = c3v;
        }
    }
}

// ---------------------------------------------------------------------------
// Cooperative fused kernel. Block bid owns planes bid*4..bid*4+3 (batch bid>>6).
// Cross-block handoffs (gap_g, hid_g) use agent-scope atomics (XCD-coherent).
// ---------------------------------------------------------------------------
__global__ __launch_bounds__(256, 8) void fused_kernel(
        const float* __restrict__ x,  const float* __restrict__ w1,
        const float* __restrict__ b1, const float* __restrict__ w2,
        const float* __restrict__ b2, float* __restrict__ out,
        float* __restrict__ gap_g,    float* __restrict__ hid_g) {
    const int tid = threadIdx.x;
    const int bid = blockIdx.x;
    const int p0  = bid * PPB;
    const int b   = bid >> 6;

    __shared__ float sm[58 * 64];
    __shared__ float lgs[PPB][9];
    __shared__ float red[4];
    float4* sm4 = (float4*)sm;

    // halo zero-fill (disjoint from interior)
    if (tid < 116) {
        const int r = (tid & 1) ? 57 : 0;
        sm[r * 64 + 3 + (tid >> 1)] = 0.f;
    } else if (tid < 228) {
        const int i = tid - 116;
        sm[(1 + (i >> 1)) * 64 + ((i & 1) ? 60 : 3)] = 0.f;
    }

    // ---- P1: gap for 4 planes; plane +3 stays in LDS ----
    for (int pl = 0; pl < 3; ++pl) {
        const float4* p4 = (const float4*)(x + (size_t)(p0 + pl) * HW_);
        float s = 0.f;
        for (int i = tid; i < HW_ / 4; i += 256) {
            float4 v = p4[i];
            s += (v.x + v.y) + (v.z + v.w);
        }
        for (int off = 32; off > 0; off >>= 1) s += __shfl_down(s, off, 64);
        if ((tid & 63) == 0) red[tid >> 6] = s;
        __syncthreads();
        if (tid == 0)
            st_agent(&gap_g[p0 + pl],
                     (red[0] + red[1] + red[2] + red[3]) * (1.0f / (float)HW_));
        __syncthreads();
    }
    {
        const float4* p4 = (const float4*)(x + (size_t)(p0 + 3) * HW_);
        float s = 0.f;
        for (int i = tid; i < HW_ / 4; i += 256) {
            float4 v = p4[i];
            const int y = i / 14, q = i - y * 14;
            sm4[(y + 1) * 16 + 1 + q] = v;
            s += (v.x + v.y) + (v.z + v.w);
        }
        for (int off = 32; off > 0; off >>= 1) s += __shfl_down(s, off, 64);
        if ((tid & 63) == 0) red[tid >> 6] = s;
        __syncthreads();
        if (tid == 0)
            st_agent(&gap_g[p0 + 3],
                     (red[0] + red[1] + red[2] + red[3]) * (1.0f / (float)HW_));
    }
    __threadfence();
    cg::this_grid().sync();
    __threadfence();

    // ---- P2: blocks 0..31 compute hid for batch = bid ----
    if (bid < B_) {
        const int j = tid >> 2;
        const int part = tid & 3;
        const float4* wr = (const float4*)(w1 + (size_t)j * C_) + part * 16;
        const float* gv = gap_g + (size_t)bid * C_ + part * 64;
        float acc = 0.f;
        #pragma unroll
        for (int q = 0; q < 16; ++q) {
            float4 w = wr[q];
            acc += w.x * ld_agent(gv + 4*q)     + w.y * ld_agent(gv + 4*q + 1)
                 + w.z * ld_agent(gv + 4*q + 2) + w.w * ld_agent(gv + 4*q + 3);
        }
        acc += __shfl_xor(acc, 1, 64);
        acc += __shfl_xor(acc, 2, 64);
        if (part == 0) {
            acc += b1[j];
            st_agent(&hid_g[bid * CR_ + j],
                     0.5f * acc * (1.0f + erff(acc * 0.7071067811865476f)));
        }
    }
    __threadfence();
    cg::this_grid().sync();
    __threadfence();

    // ---- P3: logits for 4 planes (lanes 0..35), then convs ----
    if (tid < 36) {
        const int pl = tid / 9, t = tid - pl * 9;
        const int c  = (p0 + pl) & 255;
        const float4* wr = (const float4*)(w2 + ((size_t)c * 9 + t) * CR_);
        const float* hv = hid_g + (size_t)b * CR_;
        float acc = b2[c * 9 + t];
        #pragma unroll
        for (int q = 0; q < 16; ++q) {
            float4 w = wr[q];
            acc += w.x * ld_agent(hv + 4*q)     + w.y * ld_agent(hv + 4*q + 1)
                 + w.z * ld_agent(hv + 4*q + 2) + w.w * ld_agent(hv + 4*q + 3);
        }
        lgs[pl][t] = acc;
    }
    __syncthreads();

    conv_plane(sm, lgs[3], out + (size_t)(p0 + 3) * HW_, tid);

    for (int pl = 0; pl < 3; ++pl) {
        __syncthreads();
        const float4* p4 = (const float4*)(x + (size_t)(p0 + pl) * HW_);
        for (int i = tid; i < HW_ / 4; i += 256) {
            const int y = i / 14, q = i - y * 14;
            sm4[(y + 1) * 16 + 1 + q] = p4[i];
        }
        __syncthreads();
        conv_plane(sm, lgs[pl], out + (size_t)(p0 + pl) * HW_, tid);
    }
}

// ---------------------------------------------------------------------------
// Fallback path (proven R7 structure, 61.0 us): 3 kernels.
// ---------------------------------------------------------------------------
__global__ __launch_bounds__(256) void gap_kernel(const float* __restrict__ x,
                                                  float* __restrict__ gap) {
    const int bc = blockIdx.x;
    const float4* p4 = (const float4*)(x + (size_t)bc * HW_);
    float s = 0.f;
    for (int i = threadIdx.x; i < HW_ / 4; i += 256) {
        float4 v = p4[i];
        s += (v.x + v.y) + (v.z + v.w);
    }
    for (int off = 32; off > 0; off >>= 1) s += __shfl_down(s, off, 64);
    __shared__ float ws[4];
    const int lane = threadIdx.x & 63, wid = threadIdx.x >> 6;
    if (lane == 0) ws[wid] = s;
    __syncthreads();
    if (threadIdx.x == 0) {
        float t = (ws[0] + ws[1]) + (ws[2] + ws[3]);
        gap[bc] = t * (1.0f / (float)HW_);
    }
}

__global__ __launch_bounds__(256) void hid_kernel(const float* __restrict__ gap,
                                                  const float* __restrict__ w1,
                                                  const float* __restrict__ b1,
                                                  float* __restrict__ hid_g) {
    const int b = blockIdx.x;
    const int j = threadIdx.x >> 2;
    const int part = threadIdx.x & 3;
    const float4* wr = (const float4*)(w1 + (size_t)j * C_) + part * 16;
    const float4* gv = (const float4*)(gap + (size_t)b * C_) + part * 16;
    float acc = 0.f;
    #pragma unroll
    for (int q = 0; q < 16; ++q) {
        float4 w = wr[q], g = gv[q];
        acc += w.x * g.x + w.y * g.y + w.z * g.z + w.w * g.w;
    }
    acc += __shfl_xor(acc, 1, 64);
    acc += __shfl_xor(acc, 2, 64);
    if (part == 0) {
        acc += b1[j];
        hid_g[b * CR_ + j] = 0.5f * acc * (1.0f + erff(acc * 0.7071067811865476f));
    }
}

__global__ __launch_bounds__(256) void dconv_kernel(const float* __restrict__ x,
                                                    const float* __restrict__ hid_g,
                                                    const float* __restrict__ w2,
                                                    const float* __restrict__ b2,
                                                    float* __restrict__ out) {
    const int bc = blockIdx.x;
    const int b  = bc >> 8;
    const int c  = bc & 255;
    const float* p = x + (size_t)bc * HW_;
    float* o = out + (size_t)bc * HW_;

    __shared__ float sm[58 * 64];
    __shared__ float lgs[9];
    float4* sm4 = (float4*)sm;
    const int tid = threadIdx.x;

    if (tid < 116) {
        const int r = (tid & 1) ? 57 : 0;
        sm[r * 64 + 3 + (tid >> 1)] = 0.f;
    } else if (tid < 228) {
        const int i = tid - 116;
        sm[(1 + (i >> 1)) * 64 + ((i & 1) ? 60 : 3)] = 0.f;
    }

    if (tid < 9) {
        const float4* wr = (const float4*)(w2 + ((size_t)c * 9 + tid) * CR_);
        const float4* hv = (const float4*)(hid_g + (size_t)b * CR_);
        float acc = b2[c * 9 + tid];
        #pragma unroll
        for (int q = 0; q < 16; ++q) {
            float4 w = wr[q], h = hv[q];
            acc += w.x * h.x + w.y * h.y + w.z * h.z + w.w * h.w;
        }
        lgs[tid] = acc;
    }

    const float4* p4 = (const float4*)p;
    for (int i = tid; i < HW_ / 4; i += 256) {
        const int y = i / 14, q = i - y * 14;
        sm4[(y + 1) * 16 + 1 + q] = p4[i];
    }
    __syncthreads();

    conv_plane(sm, lgs, o, tid);
}

// ---------------------------------------------------------------------------
extern "C" void kernel_launch(void* const* d_in, const int* in_sizes, int n_in,
                              void* d_out, int out_size, void* d_ws, size_t ws_size,
                              hipStream_t stream) {
    const float* x  = (const float*)d_in[0];
    const float* w1 = (const float*)d_in[1];
    const float* b1 = (const float*)d_in[2];
    const float* w2 = (const float*)d_in[3];
    const float* b2 = (const float*)d_in[4];
    float* out = (float*)d_out;

    float* gap_g = (float*)d_ws;                 // 8192 floats
    float* hid_g = gap_g + BC_;                  // 2048 floats

    void* args[] = { (void*)&x, (void*)&w1, (void*)&b1, (void*)&w2,
                     (void*)&b2, (void*)&out, (void*)&gap_g, (void*)&hid_g };
    hipError_t err = hipLaunchCooperativeKernel((const void*)fused_kernel,
                                                dim3(GRID_), dim3(256),
                                                args, 0, stream);
    if (err != hipSuccess) {
        // fallback: proven 3-kernel path
        gap_kernel<<<BC_, 256, 0, stream>>>(x, gap_g);
        hid_kernel<<<B_, 256, 0, stream>>>(gap_g, w1, b1, hid_g);
        dconv_kernel<<<BC_, 256, 0, stream>>>(x, hid_g, w2, b2, out);
    }
}

// Round 15
// 275.769 us; speedup vs baseline: 7.3293x; 7.3293x over previous
//
#include <hip/hip_runtime.h>
#include <math.h>

// Problem constants
#define B_  32
#define C_  256
#define H_  56
#define W_  56
#define CR_ 64          // C/RED
#define HW_ (H_*W_)     // 3136
#define BC_ (B_*C_)     // 8192

typedef float float2v __attribute__((ext_vector_type(2)));

// packed f32 FMA: d = a*b + c  (2 lanes of f32 per instruction)
__device__ __forceinline__ float2v pk_fma(float2v a, float2v b, float2v c) {
    float2v d;
    asm("v_pk_fma_f32 %0, %1, %2, %3" : "=v"(d) : "v"(a), "v"(b), "v"(c));
    return d;
}

// ---------------------------------------------------------------------------
// Kernel 1: gap + (last block per batch) hid.
// One block per (b,c) plane computes gap[bc]; the 256th finisher of each
// batch computes hid[b,:] = gelu(gap[b,:] @ w1^T + b1).
// ---------------------------------------------------------------------------
__global__ __launch_bounds__(256) void gap_hid_kernel(const float* __restrict__ x,
                                                      const float* __restrict__ w1,
                                                      const float* __restrict__ b1,
                                                      float* __restrict__ gap,
                                                      float* __restrict__ hid_g,
                                                      int* __restrict__ cnt) {
    const int bc = blockIdx.x;
    const int b  = bc >> 8;
    const float4* p4 = (const float4*)(x + (size_t)bc * HW_);
    float s = 0.f;
    for (int i = threadIdx.x; i < HW_ / 4; i += 256) {
        float4 v = p4[i];
        s += (v.x + v.y) + (v.z + v.w);
    }
    for (int off = 32; off > 0; off >>= 1) s += __shfl_down(s, off, 64);
    __shared__ float ws[4];
    __shared__ int last_s;
    const int lane = threadIdx.x & 63, wid = threadIdx.x >> 6;
    if (lane == 0) ws[wid] = s;
    __syncthreads();
    if (threadIdx.x == 0) {
        float t = (ws[0] + ws[1]) + (ws[2] + ws[3]);
        gap[bc] = t * (1.0f / (float)HW_);
        __threadfence();                          // publish gap[bc]
        int old = atomicAdd(&cnt[b], 1);          // device-scope
        last_s = (old == 255);
    }
    __syncthreads();
    if (!last_s) return;

    // last block of batch b: all 256 gap values are published
    __threadfence();                              // acquire side
    const int j = threadIdx.x >> 2;               // channel 0..63
    const int part = threadIdx.x & 3;             // quarter 0..3
    const float4* wr = (const float4*)(w1 + (size_t)j * C_) + part * 16;
    const float4* gv = (const float4*)(gap + (size_t)b * C_) + part * 16;
    float acc = 0.f;
    #pragma unroll
    for (int q = 0; q < 16; ++q) {
        float4 w = wr[q], g = gv[q];
        acc += w.x * g.x + w.y * g.y + w.z * g.z + w.w * g.w;
    }
    acc += __shfl_xor(acc, 1, 64);
    acc += __shfl_xor(acc, 2, 64);
    if (part == 0) {
        acc += b1[j];
        hid_g[b * CR_ + j] = 0.5f * acc * (1.0f + erff(acc * 0.7071067811865476f));
    }
}

// ---------------------------------------------------------------------------
// Kernel 2: fused logits + softmax + dynamic 3x3 depthwise conv + residual.
// Identical to the measured-best R7 kernel (61.0 us): one 256-thread block
// per plane, LDS 58x64, halo-only zero-fill, ONE barrier, pk_fma conv,
// normal (caching) loads and stores.
// ---------------------------------------------------------------------------
__global__ __launch_bounds__(256) void dconv_kernel(const float* __restrict__ x,
                                                    const float* __restrict__ hid_g,
                                                    const float* __restrict__ w2,
                                                    const float* __restrict__ b2,
                                                    float* __restrict__ out) {
    const int bc = blockIdx.x;
    const int b  = bc >> 8;
    const int c  = bc & 255;
    const float* p = x + (size_t)bc * HW_;
    float* o = out + (size_t)bc * HW_;

    __shared__ float sm[58 * 64];
    __shared__ float lgs[9];
    float4* sm4 = (float4*)sm;
    const int tid = threadIdx.x;

    // halo-only zero fill (disjoint from interior)
    if (tid < 116) {
        const int r = (tid & 1) ? 57 : 0;
        sm[r * 64 + 3 + (tid >> 1)] = 0.f;
    } else if (tid < 228) {
        const int i = tid - 116;
        sm[(1 + (i >> 1)) * 64 + ((i & 1) ? 60 : 3)] = 0.f;
    }

    // this channel's 9 logits (lanes 0..8), overlapped with staging
    if (tid < 9) {
        const float4* wr = (const float4*)(w2 + ((size_t)c * 9 + tid) * CR_);
        const float4* hv = (const float4*)(hid_g + (size_t)b * CR_);
        float acc = b2[c * 9 + tid];
        #pragma unroll
        for (int q = 0; q < 16; ++q) {
            float4 w = wr[q], h = hv[q];
            acc += w.x * h.x + w.y * h.y + w.z * h.z + w.w * h.w;
        }
        lgs[tid] = acc;
    }

    // interior stage: image rows 0..55 -> LDS rows 1..56, cols 4..59
    const float4* p4 = (const float4*)p;
    for (int i = tid; i < HW_ / 4; i += 256) {
        const int y = i / 14, q = i - y * 14;
        sm4[(y + 1) * 16 + 1 + q] = p4[i];
    }
    __syncthreads();

    // redundant per-thread softmax over the 9 taps
    float l0 = lgs[0], l1 = lgs[1], l2 = lgs[2], l3 = lgs[3], l4 = lgs[4],
          l5 = lgs[5], l6 = lgs[6], l7 = lgs[7], l8 = lgs[8];
    float mx = fmaxf(fmaxf(fmaxf(fmaxf(l0, l1), fmaxf(l2, l3)),
                           fmaxf(fmaxf(l4, l5), fmaxf(l6, l7))), l8);
    float k0 = __expf(l0 - mx), k1 = __expf(l1 - mx), k2 = __expf(l2 - mx),
          k3 = __expf(l3 - mx), k4 = __expf(l4 - mx), k5 = __expf(l5 - mx),
          k6 = __expf(l6 - mx), k7 = __expf(l7 - mx), k8 = __expf(l8 - mx);
    const float inv = 1.0f / (((k0 + k1) + (k2 + k3)) + ((k4 + k5) + (k6 + k7)) + k8);
    k0 *= inv; k1 *= inv; k2 *= inv; k3 *= inv; k4 *= inv;
    k5 *= inv; k6 *= inv; k7 *= inv; k8 *= inv;

    const float2v K0 = {k0, k0}, K1 = {k1, k1}, K2 = {k2, k2};
    const float2v K3 = {k3, k3}, K4 = {k4, k4}, K5 = {k5, k5};
    const float2v K6 = {k6, k6}, K7 = {k7, k7}, K8 = {k8, k8};

    // conv: thread = (strip s: 7 rows, col-pair g: image cols 2g,2g+1)
    if (tid < 224) {
        const int s  = tid / 28;                 // strip 0..7
        const int g  = tid - s * 28;             // col-pair 0..27
        const int y0 = s * 7;
        const float* base = sm + y0 * 64 + 3 + 2 * g;

        float a0 = base[0], a1 = base[1], a2 = base[2], a3 = base[3];
        const float* rB = base + 64;
        float b0 = rB[0], b1 = rB[1], b2 = rB[2], b3 = rB[3];

        #pragma unroll
        for (int r = 0; r < 7; ++r) {
            const float* rC = base + (r + 2) * 64;
            const float c0v = rC[0], c1v = rC[1], c2v = rC[2], c3v = rC[3];

            const float2v Am = {a0, a1}, A0 = {a1, a2}, Ap = {a2, a3};
            const float2v Bm = {b0, b1}, B0 = {b1, b2}, Bp = {b2, b3};
            const float2v Cm = {c0v, c1v}, C0 = {c1v, c2v}, Cp = {c2v, c3v};

            float2v acc = B0;                    // residual (center = input)
            acc = pk_fma(K0, Am, acc);
            acc = pk_fma(K1, A0, acc);
            acc = pk_fma(K2, Ap, acc);
            acc = pk_fma(K3, Bm, acc);
            acc = pk_fma(K4, B0, acc);
            acc = pk_fma(K5, Bp, acc);
            acc = pk_fma(K6, Cm, acc);
            acc = pk_fma(K7, C0, acc);
            acc = pk_fma(K8, Cp, acc);

            *(float2v*)(o + (y0 + r) * W_ + 2 * g) = acc;

            a0 = b0; a1 = b1; a2 = b2; a3 = b3;
            b0 = c0v; b1 = c1v; b2 = c2v; b3 = c3v;
        }
    }
}

// ---------------------------------------------------------------------------
extern "C" void kernel_launch(void* const* d_in, const int* in_sizes, int n_in,
                              void* d_out, int out_size, void* d_ws, size_t ws_size,
                              hipStream_t stream) {
    const float* x  = (const float*)d_in[0];
    const float* w1 = (const float*)d_in[1];
    const float* b1 = (const float*)d_in[2];
    const float* w2 = (const float*)d_in[3];
    const float* b2 = (const float*)d_in[4];
    float* out = (float*)d_out;

    float* gap   = (float*)d_ws;                 // 8192 floats
    float* hid_g = gap + BC_;                    // 2048 floats
    int*   cnt   = (int*)(hid_g + B_ * CR_);     // 32 ints

    hipMemsetAsync(cnt, 0, B_ * sizeof(int), stream);   // capture-safe
    gap_hid_kernel<<<BC_, 256, 0, stream>>>(x, w1, b1, gap, hid_g, cnt);
    dconv_kernel<<<BC_, 256, 0, stream>>>(x, hid_g, w2, b2, out);
}